// Round 1
// baseline (60.074 us; speedup 1.0000x reference)
//
#include <hip/hip_runtime.h>
#include <math.h>

#define B_ 8
#define N_ 128
#define M_ 256
#define F_ 256

#define LOG2E2 2.8853900817779268f  // 2*log2(e)

// ---------------------------------------------------------------------------
// K1: u[r][g] = (x[r,:] . Uw[g,:] + Ub[g]) * 2log2e       r = b*N+n (1024 rows)
// Tiled f32 GEMM (both operands row-major with f fast: C = A * B^T).
// ---------------------------------------------------------------------------
#define K1_BM 32
#define K1_BN 64
#define K1_BK 32

__global__ __launch_bounds__(256) void k1_gemm(const float* __restrict__ x,
                                               const float* __restrict__ Uw,
                                               const float* __restrict__ Ub,
                                               float* __restrict__ u) {
  __shared__ float As[K1_BK][K1_BM + 1];
  __shared__ float Bs[K1_BK][K1_BN + 1];
  const int tid  = threadIdx.x;
  const int row0 = blockIdx.x * K1_BM;
  const int col0 = blockIdx.y * K1_BN;
  const int tc = (tid & 15) * 4;   // 16 col-groups of 4
  const int tr = (tid >> 4) * 2;   // 16 row-groups of 2
  float acc[2][4] = {};

  for (int k0 = 0; k0 < F_; k0 += K1_BK) {
    // stage A: 32 rows x 32 k  (256 float4, 1 per thread), store transposed
    {
      const int r = tid >> 3, c = (tid & 7) * 4;
      const float4 v = *(const float4*)&x[(row0 + r) * F_ + k0 + c];
      As[c + 0][r] = v.x; As[c + 1][r] = v.y; As[c + 2][r] = v.z; As[c + 3][r] = v.w;
    }
    // stage B: 64 g x 32 k (512 float4, 2 per thread)
#pragma unroll
    for (int i0 = 0; i0 < 2; ++i0) {
      const int i = tid + i0 * 256;
      const int g = i >> 3, c = (i & 7) * 4;
      const float4 v = *(const float4*)&Uw[(col0 + g) * F_ + k0 + c];
      Bs[c + 0][g] = v.x; Bs[c + 1][g] = v.y; Bs[c + 2][g] = v.z; Bs[c + 3][g] = v.w;
    }
    __syncthreads();
#pragma unroll
    for (int k = 0; k < K1_BK; ++k) {
      const float a0 = As[k][tr], a1 = As[k][tr + 1];
      const float b0 = Bs[k][tc + 0], b1 = Bs[k][tc + 1];
      const float b2 = Bs[k][tc + 2], b3 = Bs[k][tc + 3];
      acc[0][0] = fmaf(a0, b0, acc[0][0]);
      acc[0][1] = fmaf(a0, b1, acc[0][1]);
      acc[0][2] = fmaf(a0, b2, acc[0][2]);
      acc[0][3] = fmaf(a0, b3, acc[0][3]);
      acc[1][0] = fmaf(a1, b0, acc[1][0]);
      acc[1][1] = fmaf(a1, b1, acc[1][1]);
      acc[1][2] = fmaf(a1, b2, acc[1][2]);
      acc[1][3] = fmaf(a1, b3, acc[1][3]);
    }
    __syncthreads();
  }
#pragma unroll
  for (int r = 0; r < 2; ++r) {
    float4 o;
    o.x = (acc[r][0] + Ub[col0 + tc + 0]) * LOG2E2;
    o.y = (acc[r][1] + Ub[col0 + tc + 1]) * LOG2E2;
    o.z = (acc[r][2] + Ub[col0 + tc + 2]) * LOG2E2;
    o.w = (acc[r][3] + Ub[col0 + tc + 3]) * LOG2E2;
    *(float4*)&u[(row0 + tr + r) * F_ + col0 + tc] = o;
  }
}

// ---------------------------------------------------------------------------
// K2: for tile (b, nc: 16 n's, mc: 64 m's) compute
//     alpha[n,m] = sum_f tanh-from-scaled(us * y) * Ww[f]   (W_b dropped:
//     softmax/max are shift-invariant)
// and reduce to partial maxes:
//     rpart[b][mc][n] = max over tile's 64 m
//     cpart[b][nc][m] = max over tile's 16 n
// tanh(x) = 1 - 2*rcp(exp2(arg)+1)   with arg = (2 log2e * x) prefolded in u.
// ---------------------------------------------------------------------------
#define NT 16
#define MT 64
#define FB 64

__global__ __launch_bounds__(512) void k2_alpha(const float* __restrict__ u,
                                                const float* __restrict__ y,
                                                const float* __restrict__ Ww,
                                                float* __restrict__ rpart,
                                                float* __restrict__ cpart) {
  __shared__ float us[NT][FB + 1];
  __shared__ float ys[MT][FB + 1];
  __shared__ float ww[FB];
  __shared__ float cm[8][64];

  const int tid = threadIdx.x;
  const int mc = blockIdx.x;   // 0..3
  const int nc = blockIdx.y;   // 0..7
  const int b  = blockIdx.z;   // 0..7
  const int tx = tid & 63;     // m lane
  const int ty = tid >> 6;     // wave id 0..7 (n group)
  const int n0 = nc * NT, m0 = mc * MT;

  float acc0 = 0.f, acc1 = 0.f;

  for (int f0 = 0; f0 < F_; f0 += FB) {
    __syncthreads();
    // stage u tile: 16 x 64 floats (256 float4)
    for (int i = tid; i < (NT * FB) / 4; i += 512) {
      const int r = i >> 4, c = (i & 15) * 4;
      const float4 v = *(const float4*)&u[(b * N_ + n0 + r) * F_ + f0 + c];
      us[r][c + 0] = v.x; us[r][c + 1] = v.y; us[r][c + 2] = v.z; us[r][c + 3] = v.w;
    }
    // stage y tile: 64 x 64 floats (1024 float4)
    for (int i = tid; i < (MT * FB) / 4; i += 512) {
      const int r = i >> 4, c = (i & 15) * 4;
      const float4 v = *(const float4*)&y[(b * M_ + m0 + r) * F_ + f0 + c];
      ys[r][c + 0] = v.x; ys[r][c + 1] = v.y; ys[r][c + 2] = v.z; ys[r][c + 3] = v.w;
    }
    if (tid < FB) ww[tid] = Ww[f0 + tid];
    __syncthreads();

#pragma unroll 8
    for (int f = 0; f < FB; ++f) {
      const float yv = ys[tx][f];
      const float w  = ww[f];
      const float a0 = us[ty][f] * yv;        // already scaled by 2log2e
      const float a1 = us[ty + 8][f] * yv;
      const float e0 = __builtin_amdgcn_exp2f(a0);
      const float e1 = __builtin_amdgcn_exp2f(a1);
      const float t0 = fmaf(-2.f, __builtin_amdgcn_rcpf(e0 + 1.f), 1.f);
      const float t1 = fmaf(-2.f, __builtin_amdgcn_rcpf(e1 + 1.f), 1.f);
      acc0 = fmaf(t0, w, acc0);
      acc1 = fmaf(t1, w, acc1);
    }
  }

  // row max over the tile's 64 m (full-wave butterfly)
  float r0 = acc0, r1 = acc1;
#pragma unroll
  for (int s = 32; s; s >>= 1) {
    r0 = fmaxf(r0, __shfl_xor(r0, s));
    r1 = fmaxf(r1, __shfl_xor(r1, s));
  }
  if (tx == 0) {
    rpart[(b * 4 + mc) * N_ + n0 + ty]     = r0;
    rpart[(b * 4 + mc) * N_ + n0 + ty + 8] = r1;
  }

  // col max over the tile's 16 n (cross-wave via LDS)
  cm[ty][tx] = fmaxf(acc0, acc1);
  __syncthreads();
  if (tid < 64) {
    float v = cm[0][tid];
#pragma unroll
    for (int wv = 1; wv < 8; ++wv) v = fmaxf(v, cm[wv][tid]);
    cpart[(b * 8 + nc) * M_ + m0 + tid] = v;
  }
}

// ---------------------------------------------------------------------------
// K3: per-batch finish: reduce partial maxes, two softmaxes, two pooled dots.
// ---------------------------------------------------------------------------
__global__ __launch_bounds__(256) void k3_final(const float* __restrict__ x,
                                                const float* __restrict__ y,
                                                const float* __restrict__ rpart,
                                                const float* __restrict__ cpart,
                                                float* __restrict__ out) {
  const int b = blockIdx.x;
  const int tid = threadIdx.x;
  __shared__ float xw[N_];
  __shared__ float yw[M_];
  __shared__ float red[4];

  // ---- x attention: softmax over n of rowmax ----
  float rv = -INFINITY;
  if (tid < N_) {
#pragma unroll
    for (int mc = 0; mc < 4; ++mc)
      rv = fmaxf(rv, rpart[(b * 4 + mc) * N_ + tid]);
  }
  // block max
  float m1 = rv;
#pragma unroll
  for (int s = 32; s; s >>= 1) m1 = fmaxf(m1, __shfl_xor(m1, s));
  if ((tid & 63) == 0) red[tid >> 6] = m1;
  __syncthreads();
  m1 = fmaxf(fmaxf(red[0], red[1]), fmaxf(red[2], red[3]));
  __syncthreads();
  const float e1 = (tid < N_) ? __expf(rv - m1) : 0.f;
  float s1 = e1;
#pragma unroll
  for (int s = 32; s; s >>= 1) s1 += __shfl_xor(s1, s);
  if ((tid & 63) == 0) red[tid >> 6] = s1;
  __syncthreads();
  s1 = red[0] + red[1] + red[2] + red[3];
  if (tid < N_) xw[tid] = e1 / s1;
  __syncthreads();

  // ---- y attention: softmax over m of colmax ----
  float cv = -INFINITY;
#pragma unroll
  for (int nc = 0; nc < 8; ++nc)
    cv = fmaxf(cv, cpart[(b * 8 + nc) * M_ + tid]);
  float m2 = cv;
#pragma unroll
  for (int s = 32; s; s >>= 1) m2 = fmaxf(m2, __shfl_xor(m2, s));
  if ((tid & 63) == 0) red[tid >> 6] = m2;
  __syncthreads();
  m2 = fmaxf(fmaxf(red[0], red[1]), fmaxf(red[2], red[3]));
  __syncthreads();
  const float e2 = __expf(cv - m2);
  float s2 = e2;
#pragma unroll
  for (int s = 32; s; s >>= 1) s2 += __shfl_xor(s2, s);
  if ((tid & 63) == 0) red[tid >> 6] = s2;
  __syncthreads();
  s2 = red[0] + red[1] + red[2] + red[3];
  yw[tid] = e2 / s2;
  __syncthreads();

  // ---- pooled outputs (tid = feature index 0..255) ----
  float accx = 0.f;
#pragma unroll 4
  for (int n = 0; n < N_; ++n)
    accx = fmaf(xw[n], x[(b * N_ + n) * F_ + tid], accx);
  out[b * (2 * F_) + tid] = accx;

  float accy = 0.f;
#pragma unroll 4
  for (int m = 0; m < M_; ++m)
    accy = fmaf(yw[m], y[(b * M_ + m) * F_ + tid], accy);
  out[b * (2 * F_) + F_ + tid] = accy;
}

// ---------------------------------------------------------------------------
extern "C" void kernel_launch(void* const* d_in, const int* in_sizes, int n_in,
                              void* d_out, int out_size, void* d_ws, size_t ws_size,
                              hipStream_t stream) {
  (void)in_sizes; (void)n_in; (void)out_size; (void)ws_size;
  const float* x  = (const float*)d_in[0];
  const float* y  = (const float*)d_in[1];
  const float* Uw = (const float*)d_in[2];
  const float* Ub = (const float*)d_in[3];
  const float* Ww = (const float*)d_in[4];
  // d_in[5] (W_b) intentionally unused: softmax/max pipeline is shift-invariant.

  float* u     = (float*)d_ws;                 // [B][N][F]   262144 f
  float* rpart = u + B_ * N_ * F_;             // [B][4][N]     4096 f
  float* cpart = rpart + B_ * 4 * N_;          // [B][8][M]    16384 f
  float* out   = (float*)d_out;

  k1_gemm<<<dim3((B_ * N_) / K1_BM, F_ / K1_BN), 256, 0, stream>>>(x, Uw, Ub, u);
  k2_alpha<<<dim3(M_ / MT, N_ / NT, B_), 512, 0, stream>>>(u, y, Ww, rpart, cpart);
  k3_final<<<dim3(B_), 256, 0, stream>>>(x, y, rpart, cpart, out);
}

// Round 2
// 53.346 us; speedup vs baseline: 1.1261x; 1.1261x over previous
//
#include <hip/hip_runtime.h>
#include <math.h>

#define B_ 8
#define N_ 128
#define M_ 256
#define F_ 256

#define LOG2E2 2.8853900817779268f  // 2*log2(e)

// ---------------------------------------------------------------------------
// K1: u[r][g] = (x[r,:] . Uw[g,:] + Ub[g]) * 2log2e       r = b*N+n (1024 rows)
// ---------------------------------------------------------------------------
#define K1_BM 32
#define K1_BN 64
#define K1_BK 32

__global__ __launch_bounds__(256) void k1_gemm(const float* __restrict__ x,
                                               const float* __restrict__ Uw,
                                               const float* __restrict__ Ub,
                                               float* __restrict__ u) {
  __shared__ float As[K1_BK][K1_BM + 1];
  __shared__ float Bs[K1_BK][K1_BN + 1];
  const int tid  = threadIdx.x;
  const int row0 = blockIdx.x * K1_BM;
  const int col0 = blockIdx.y * K1_BN;
  const int tc = (tid & 15) * 4;
  const int tr = (tid >> 4) * 2;
  float acc[2][4] = {};

  for (int k0 = 0; k0 < F_; k0 += K1_BK) {
    {
      const int r = tid >> 3, c = (tid & 7) * 4;
      const float4 v = *(const float4*)&x[(row0 + r) * F_ + k0 + c];
      As[c + 0][r] = v.x; As[c + 1][r] = v.y; As[c + 2][r] = v.z; As[c + 3][r] = v.w;
    }
#pragma unroll
    for (int i0 = 0; i0 < 2; ++i0) {
      const int i = tid + i0 * 256;
      const int g = i >> 3, c = (i & 7) * 4;
      const float4 v = *(const float4*)&Uw[(col0 + g) * F_ + k0 + c];
      Bs[c + 0][g] = v.x; Bs[c + 1][g] = v.y; Bs[c + 2][g] = v.z; Bs[c + 3][g] = v.w;
    }
    __syncthreads();
#pragma unroll
    for (int k = 0; k < K1_BK; ++k) {
      const float a0 = As[k][tr], a1 = As[k][tr + 1];
      const float b0 = Bs[k][tc + 0], b1 = Bs[k][tc + 1];
      const float b2 = Bs[k][tc + 2], b3 = Bs[k][tc + 3];
      acc[0][0] = fmaf(a0, b0, acc[0][0]);
      acc[0][1] = fmaf(a0, b1, acc[0][1]);
      acc[0][2] = fmaf(a0, b2, acc[0][2]);
      acc[0][3] = fmaf(a0, b3, acc[0][3]);
      acc[1][0] = fmaf(a1, b0, acc[1][0]);
      acc[1][1] = fmaf(a1, b1, acc[1][1]);
      acc[1][2] = fmaf(a1, b2, acc[1][2]);
      acc[1][3] = fmaf(a1, b3, acc[1][3]);
    }
    __syncthreads();
  }
#pragma unroll
  for (int r = 0; r < 2; ++r) {
    float4 o;
    o.x = (acc[r][0] + Ub[col0 + tc + 0]) * LOG2E2;
    o.y = (acc[r][1] + Ub[col0 + tc + 1]) * LOG2E2;
    o.z = (acc[r][2] + Ub[col0 + tc + 2]) * LOG2E2;
    o.w = (acc[r][3] + Ub[col0 + tc + 3]) * LOG2E2;
    *(float4*)&u[(row0 + tr + r) * F_ + col0 + tc] = o;
  }
}

// ---------------------------------------------------------------------------
// K2: tile (b, 16 n, 64 m). alpha[n,m] = Wsum - 2 * sum_f Ww[f]*rcp(exp2(us*y)+1)
// us/Ww read via wave-uniform scalar loads (no LDS); only y staged in LDS.
// Reduces alpha to rpart (max over m-tile) and cpart (max over n-tile).
// ---------------------------------------------------------------------------
#define NT 16
#define MT 64
#define FB 128

__global__ __launch_bounds__(512) void k2_alpha(const float* __restrict__ u,
                                                const float* __restrict__ y,
                                                const float* __restrict__ Ww,
                                                float* __restrict__ rpart,
                                                float* __restrict__ cpart) {
  __shared__ float ys[MT][FB + 1];   // row-major, +1 pad: (tx+f)%32 banks, 2-way free
  __shared__ float cm[8][64];

  const int tid = threadIdx.x;
  const int mc = blockIdx.x;   // 0..3
  const int nc = blockIdx.y;   // 0..7
  const int b  = blockIdx.z;   // 0..7
  const int tx = tid & 63;                                       // m lane
  const int ty = __builtin_amdgcn_readfirstlane(tid >> 6);       // wave id -> SGPR
  const int n0 = nc * NT, m0 = mc * MT;

  const float* __restrict__ u0 = u + (size_t)(b * N_ + n0 + ty) * F_;
  const float* __restrict__ u1 = u0 + 8 * F_;

  float acc0 = 0.f, acc1 = 0.f, wsum = 0.f;

  for (int f0 = 0; f0 < F_; f0 += FB) {
    __syncthreads();
    // stage y tile: 64 m x 128 f  (2048 float4 over 512 threads)
    for (int i = tid; i < (MT * FB) / 4; i += 512) {
      const int r = i >> 5;            // m row 0..63
      const int c = (i & 31) * 4;      // f   0..124
      const float4 v = *(const float4*)&y[(size_t)(b * M_ + m0 + r) * F_ + f0 + c];
      ys[r][c + 0] = v.x; ys[r][c + 1] = v.y; ys[r][c + 2] = v.z; ys[r][c + 3] = v.w;
    }
    __syncthreads();

    for (int f = 0; f < FB; f += 4) {
      const float4 uv0 = *(const float4*)&u0[f0 + f];   // wave-uniform -> s_load
      const float4 uv1 = *(const float4*)&u1[f0 + f];
      const float4 wv  = *(const float4*)&Ww[f0 + f];
      const float* up0 = (const float*)&uv0;
      const float* up1 = (const float*)&uv1;
      const float* wp  = (const float*)&wv;
      wsum += wp[0] + wp[1] + wp[2] + wp[3];
#pragma unroll
      for (int j = 0; j < 4; ++j) {
        const float yv = ys[tx][f + j];
        const float e0 = __builtin_amdgcn_exp2f(up0[j] * yv);
        const float e1 = __builtin_amdgcn_exp2f(up1[j] * yv);
        acc0 = fmaf(wp[j], __builtin_amdgcn_rcpf(e0 + 1.f), acc0);
        acc1 = fmaf(wp[j], __builtin_amdgcn_rcpf(e1 + 1.f), acc1);
      }
    }
  }

  const float alpha0 = wsum - 2.f * acc0;   // alpha for (n0+ty,    m0+tx)
  const float alpha1 = wsum - 2.f * acc1;   // alpha for (n0+ty+8,  m0+tx)

  // row max over the tile's 64 m
  float r0 = alpha0, r1 = alpha1;
#pragma unroll
  for (int s = 32; s; s >>= 1) {
    r0 = fmaxf(r0, __shfl_xor(r0, s));
    r1 = fmaxf(r1, __shfl_xor(r1, s));
  }
  if (tx == 0) {
    rpart[(b * 4 + mc) * N_ + n0 + ty]     = r0;
    rpart[(b * 4 + mc) * N_ + n0 + ty + 8] = r1;
  }

  // col max over the tile's 16 n
  cm[tid >> 6][tx] = fmaxf(alpha0, alpha1);
  __syncthreads();
  if (tid < 64) {
    float v = cm[0][tid];
#pragma unroll
    for (int wv2 = 1; wv2 < 8; ++wv2) v = fmaxf(v, cm[wv2][tid]);
    cpart[(b * 8 + nc) * M_ + m0 + tid] = v;
  }
}

// ---------------------------------------------------------------------------
// K3: per-batch finish. 1024 threads: softmaxes, then dots split 4-way over
// the sum dimension with LDS partial reduce.
// ---------------------------------------------------------------------------
__global__ __launch_bounds__(1024) void k3_final(const float* __restrict__ x,
                                                 const float* __restrict__ y,
                                                 const float* __restrict__ rpart,
                                                 const float* __restrict__ cpart,
                                                 float* __restrict__ out) {
  const int b = blockIdx.x;
  const int tid = threadIdx.x;
  const int wv = tid >> 6;
  __shared__ float xw[N_];
  __shared__ float yw[M_];
  __shared__ float red[16];
  __shared__ float part[4][256];

  // ---- x attention: softmax over n of rowmax ----
  float rv = -INFINITY;
  if (tid < N_) {
#pragma unroll
    for (int mc = 0; mc < 4; ++mc)
      rv = fmaxf(rv, rpart[(b * 4 + mc) * N_ + tid]);
  }
  float m1 = rv;
#pragma unroll
  for (int s = 32; s; s >>= 1) m1 = fmaxf(m1, __shfl_xor(m1, s));
  if ((tid & 63) == 0) red[wv] = m1;
  __syncthreads();
  m1 = red[0];
#pragma unroll
  for (int w = 1; w < 16; ++w) m1 = fmaxf(m1, red[w]);
  __syncthreads();
  const float e1 = (tid < N_) ? __expf(rv - m1) : 0.f;
  float s1 = e1;
#pragma unroll
  for (int s = 32; s; s >>= 1) s1 += __shfl_xor(s1, s);
  if ((tid & 63) == 0) red[wv] = s1;
  __syncthreads();
  s1 = 0.f;
#pragma unroll
  for (int w = 0; w < 16; ++w) s1 += red[w];
  if (tid < N_) xw[tid] = e1 / s1;
  __syncthreads();

  // ---- y attention: softmax over m of colmax ----
  float cv = -INFINITY;
  if (tid < M_) {
#pragma unroll
    for (int nc = 0; nc < 8; ++nc)
      cv = fmaxf(cv, cpart[(b * 8 + nc) * M_ + tid]);
  }
  float m2 = cv;
#pragma unroll
  for (int s = 32; s; s >>= 1) m2 = fmaxf(m2, __shfl_xor(m2, s));
  if ((tid & 63) == 0) red[wv] = m2;
  __syncthreads();
  m2 = red[0];
#pragma unroll
  for (int w = 1; w < 16; ++w) m2 = fmaxf(m2, red[w]);
  __syncthreads();
  const float e2 = (tid < M_) ? __expf(cv - m2) : 0.f;
  float s2 = e2;
#pragma unroll
  for (int s = 32; s; s >>= 1) s2 += __shfl_xor(s2, s);
  if ((tid & 63) == 0) red[wv] = s2;
  __syncthreads();
  s2 = 0.f;
#pragma unroll
  for (int w = 0; w < 16; ++w) s2 += red[w];
  if (tid < M_) yw[tid] = e2 / s2;
  __syncthreads();

  // ---- pooled outputs, 4-way split over sum dimension ----
  const int q = tid >> 8;      // 0..3
  const int f = tid & 255;

  float accx = 0.f;
#pragma unroll 4
  for (int n = q; n < N_; n += 4)
    accx = fmaf(xw[n], x[(size_t)(b * N_ + n) * F_ + f], accx);
  part[q][f] = accx;
  __syncthreads();
  if (tid < 256)
    out[b * (2 * F_) + f] = part[0][f] + part[1][f] + part[2][f] + part[3][f];
  __syncthreads();

  float accy = 0.f;
#pragma unroll 4
  for (int m = q; m < M_; m += 4)
    accy = fmaf(yw[m], y[(size_t)(b * M_ + m) * F_ + f], accy);
  part[q][f] = accy;
  __syncthreads();
  if (tid < 256)
    out[b * (2 * F_) + F_ + f] = part[0][f] + part[1][f] + part[2][f] + part[3][f];
}

// ---------------------------------------------------------------------------
extern "C" void kernel_launch(void* const* d_in, const int* in_sizes, int n_in,
                              void* d_out, int out_size, void* d_ws, size_t ws_size,
                              hipStream_t stream) {
  (void)in_sizes; (void)n_in; (void)out_size; (void)ws_size;
  const float* x  = (const float*)d_in[0];
  const float* y  = (const float*)d_in[1];
  const float* Uw = (const float*)d_in[2];
  const float* Ub = (const float*)d_in[3];
  const float* Ww = (const float*)d_in[4];
  // d_in[5] (W_b) unused: softmax/max pipeline is shift-invariant.

  float* u     = (float*)d_ws;                 // [B][N][F]   262144 f
  float* rpart = u + B_ * N_ * F_;             // [B][4][N]     4096 f
  float* cpart = rpart + B_ * 4 * N_;          // [B][8][M]    16384 f
  float* out   = (float*)d_out;

  k1_gemm<<<dim3((B_ * N_) / K1_BM, F_ / K1_BN), 256, 0, stream>>>(x, Uw, Ub, u);
  k2_alpha<<<dim3(M_ / MT, N_ / NT, B_), 512, 0, stream>>>(u, y, Ww, rpart, cpart);
  k3_final<<<dim3(B_), 1024, 0, stream>>>(x, y, rpart, cpart, out);
}